// Round 15
// baseline (58.343 us; speedup 1.0000x reference)
//
#include <hip/hip_runtime.h>

#define NBINS 256
#define EPSF 1e-12f

typedef float v4f __attribute__((ext_vector_type(4)));

// 3-band fused kernel: grid = 512 slices x 3 bands, 256 threads (4 waves).
// Block (nc, band) computes ent rows {band, band+1} (8 tiles, 2 per wave,
// register-double-buffered) and writes the output band that depends on them:
//   band 0 -> rows 0-95 (ent 0,1) | band 1 -> 96-159 (1,2) | band 2 -> 160-255 (2,3)
// Bands 0/2 interleave their edge chunk (rows 0-31 / 224-255, single ent row)
// after the first PROCESS. Tile rows 1,2 are hist'd by two bands each (1.5x
// hist, re-reads L2/L3-absorbed); identical math -> identical ent -> no seams.
// 1536 blocks -> 4 blocks/CU resident (16 waves/CU) + staggered 2nd round.
// Plain stores (R10), cheap fma binning (R8), wave-local hist (R5).
__global__ __launch_bounds__(256, 2) void fused_kernel(const float* __restrict__ x,
                                                       float* __restrict__ out) {
    const int bid  = blockIdx.x;
    const unsigned nc = (unsigned)bid / 3u;       // 0..511
    const int band = bid - (int)nc * 3;           // 0,1,2
    const int s_lo = band;                        // ent rows s_lo, s_lo+1
    const int t    = threadIdx.x;
    const int lane = t & 63;
    const int wave = t >> 6;                      // tile COLUMN

    __shared__ unsigned int hist[4][NBINS];       // 4 KB, wave-private
    __shared__ float ent_s[8];                    // 2x4 local entropy rows

    const float* cbase = x + ((size_t)nc << 16) + (size_t)wave * 64;
    unsigned int* h = hist[wave];

    v4f va[16], vb[16];

#define ISSUE(buf, s)                                                             \
    _Pragma("unroll")                                                             \
    for (int k = 0; k < 16; ++k) {                                                \
        const int f = lane + (k << 6);        /* float4 idx 0..1023 */            \
        buf[k] = *reinterpret_cast<const v4f*>(                                   \
            cbase + (size_t)(s) * (64 * 256) + (size_t)(f >> 4) * 256 + (f & 15) * 4); \
    }

// PROCESS tile in buf (global tile row s); store entropy to local row le.
#define PROCESS(buf, le)                                                          \
    {                                                                             \
        float lmin = INFINITY, lmax = -INFINITY;                                  \
        _Pragma("unroll")                                                         \
        for (int k = 0; k < 16; ++k) {                                            \
            lmin = fminf(lmin, fminf(fminf(buf[k].x, buf[k].y),                   \
                                     fminf(buf[k].z, buf[k].w)));                 \
            lmax = fmaxf(lmax, fmaxf(fmaxf(buf[k].x, buf[k].y),                   \
                                     fmaxf(buf[k].z, buf[k].w)));                 \
        }                                                                         \
        _Pragma("unroll")                                                         \
        for (int off = 32; off > 0; off >>= 1) {                                  \
            lmin = fminf(lmin, __shfl_xor(lmin, off));                            \
            lmax = fmaxf(lmax, __shfl_xor(lmax, off));                            \
        }                                                                         \
        uint4 z; z.x = z.y = z.z = z.w = 0u;  /* same-wave DS ops in-order */     \
        reinterpret_cast<uint4*>(h)[lane] = z;                                    \
        const float width = (lmax - lmin) * (1.0f / NBINS);                       \
        const float wsafe = (width > 0.0f) ? width : 1.0f;                        \
        const float inv   = 1.0f / wsafe;                                         \
        const float coff  = -lmin * inv;                                          \
        _Pragma("unroll")                                                         \
        for (int k = 0; k < 16; ++k) {                                            \
            float vals[4] = {buf[k].x, buf[k].y, buf[k].z, buf[k].w};             \
            _Pragma("unroll")                                                     \
            for (int j = 0; j < 4; ++j) {                                         \
                /* arg >= -eps; trunc==floor for >=0, tiny negatives -> 0 */      \
                int bin = (int)fmaf(vals[j], inv, coff);                          \
                bin = min(bin, 255);                                              \
                atomicAdd(&h[bin], 1u);                                           \
            }                                                                     \
        }                                                                         \
        const uint4 c    = reinterpret_cast<const uint4*>(h)[lane];               \
        const float pden = inv * (1.0f / 4096.0f);  /* 1/(4096*wsafe) */          \
        const float p0 = (float)c.x * pden + EPSF;                                \
        const float p1 = (float)c.y * pden + EPSF;                                \
        const float p2 = (float)c.z * pden + EPSF;                                \
        const float p3 = (float)c.w * pden + EPSF;                                \
        float s_ = p0 + p1 + p2 + p3;                                             \
        _Pragma("unroll")                                                         \
        for (int off = 32; off > 0; off >>= 1) s_ += __shfl_xor(s_, off);         \
        const float itot = 1.0f / s_;                                             \
        const float q0 = p0 * itot, q1 = p1 * itot;                               \
        const float q2 = p2 * itot, q3 = p3 * itot;                               \
        float e = q0 * log2f(q0) + q1 * log2f(q1)                                 \
                + q2 * log2f(q2) + q3 * log2f(q3);                                \
        _Pragma("unroll")                                                         \
        for (int off = 32; off > 0; off >>= 1) e += __shfl_xor(e, off);           \
        if (lane == 0) ent_s[((le) << 2) + wave] = -e;                            \
    }

    // ---- horizontal upsample weights (lane = x4), hoisted once ----
    const int x4 = lane;
    const int ix = (int)floorf(((x4 << 2) + 0.5f) * 0.015625f - 0.5f);
    const int x0 = max(ix, 0), x1 = min(ix + 1, 3);
    v4f wv[4];
#pragma unroll
    for (int j = 0; j < 4; ++j) {
        const float fx = ((x4 << 2) + j + 0.5f) * 0.015625f - 0.5f;
        const float wx = fx - floorf(fx);
        const float a  = 1.0f - wx, bb = wx;
        wv[j].x = ((x0 == 0) ? a : 0.0f) + ((x1 == 0) ? bb : 0.0f);
        wv[j].y = ((x0 == 1) ? a : 0.0f) + ((x1 == 1) ? bb : 0.0f);
        wv[j].z = ((x0 == 2) ? a : 0.0f) + ((x1 == 2) ? bb : 0.0f);
        wv[j].w = ((x0 == 3) ? a : 0.0f) + ((x1 == 3) ? bb : 0.0f);
    }
    const v4f* er = reinterpret_cast<const v4f*>(ent_s);   // 2 local rows of 4
    v4f* out4 = reinterpret_cast<v4f*>(out) + ((size_t)nc << 14);

    // write nrows/4 rows per wave starting at ystart (wave chunks)
#define WR(ystart, nrows)                                                         \
    _Pragma("unroll")                                                             \
    for (int i = 0; i < (nrows) / 4; ++i) {                                       \
        const int   y   = (ystart) + wave * ((nrows) / 4) + i;                    \
        const float fy  = (y + 0.5f) * 0.015625f - 0.5f;                          \
        const float fiy = floorf(fy);                                             \
        const float wy  = fy - fiy;                                               \
        const int   iy  = (int)fiy;                                               \
        const int   l0  = max(iy, 0) - s_lo, l1 = min(iy + 1, 3) - s_lo;          \
        const v4f r0 = er[l0];            /* uniform per wave -> broadcast */     \
        const v4f r1 = er[l1];                                                    \
        v4f rv = r0 * (1.0f - wy) + r1 * wy;                                      \
        v4f o;                                                                    \
        o.x = rv.x * wv[0].x + rv.y * wv[0].y + rv.z * wv[0].z + rv.w * wv[0].w;  \
        o.y = rv.x * wv[1].x + rv.y * wv[1].y + rv.z * wv[1].z + rv.w * wv[1].w;  \
        o.z = rv.x * wv[2].x + rv.y * wv[2].y + rv.z * wv[2].z + rv.w * wv[2].w;  \
        o.w = rv.x * wv[3].x + rv.y * wv[3].y + rv.z * wv[3].z + rv.w * wv[3].w;  \
        out4[(y << 6) + lane] = o;                                                \
    }

    if (band == 0) {
        // ent rows 0,1 -> output rows 0..95 (0-31 need row 0 only)
        ISSUE(va, 0)
        ISSUE(vb, 1)
        PROCESS(va, 0)      // ent row 0
        __syncthreads();
        WR(0, 32)           // rows 0..31 (ent row 0 only)
        PROCESS(vb, 1)      // ent row 1
        __syncthreads();
        WR(32, 64)          // rows 32..95 (ent rows 0,1)
    } else if (band == 1) {
        // ent rows 1,2 -> output rows 96..159
        ISSUE(va, 1)
        ISSUE(vb, 2)
        PROCESS(va, 0)      // ent row 1 (local 0)
        PROCESS(vb, 1)      // ent row 2 (local 1)
        __syncthreads();
        WR(96, 64)          // rows 96..159 (ent rows 1,2)
    } else {
        // ent rows 2,3 -> output rows 160..255 (224-255 need row 3 only)
        ISSUE(va, 3)
        ISSUE(vb, 2)
        PROCESS(va, 1)      // ent row 3 (local 1)
        __syncthreads();
        WR(224, 32)         // rows 224..255 (ent row 3 only)
        PROCESS(vb, 0)      // ent row 2 (local 0)
        __syncthreads();
        WR(160, 64)         // rows 160..223 (ent rows 2,3)
    }

#undef ISSUE
#undef PROCESS
#undef WR
}

extern "C" void kernel_launch(void* const* d_in, const int* in_sizes, int n_in,
                              void* d_out, int out_size, void* d_ws, size_t ws_size,
                              hipStream_t stream) {
    const float* x   = (const float*)d_in[0];
    float*       out = (float*)d_out;
    fused_kernel<<<1536, 256, 0, stream>>>(x, out);
}

// Round 16
// 51.633 us; speedup vs baseline: 1.1300x; 1.1300x over previous
//
#include <hip/hip_runtime.h>

#define NBINS 256
#define EPSF 1e-12f

typedef float v4f __attribute__((ext_vector_type(4)));

// 8-wave fused kernel: 512 blocks x 512 threads, block = one (n,c) slice.
// Wave w (0..7): column = w&3; waves 0-3 process tile rows 0 then 1, waves
// 4-7 process rows 3 then 2 (each 2 tiles, register-double-buffered). After
// the first PROCESS round ent rows 0 AND 3 are complete -> write the edge
// bands (rows 0-31 need only r0; 224-255 only r3). After the second round
// write rows 32-223. Critical path = 2 serial PROCESS stages (R11 had 4)
// and 16 waves/CU (R11 had 8) feed the DS/VALU/HBM pipes.
// Plain stores (R10), cheap fma binning (R8), wave-private hist (R5).
__global__ __launch_bounds__(512, 2) void fused_kernel(const float* __restrict__ x,
                                                       float* __restrict__ out) {
    const int nc   = blockIdx.x;              // 0..511
    const int t    = threadIdx.x;
    const int lane = t & 63;
    const int wave = t >> 6;                  // 0..7
    const int col  = wave & 3;                // tile column
    const int rA   = (wave < 4) ? 0 : 3;      // first tile row
    const int rB   = (wave < 4) ? 1 : 2;      // second tile row

    __shared__ unsigned int hist[8][NBINS];   // 8 KB, wave-private
    __shared__ float ent_s[16];               // 4x4 entropy map, row-major

    const float* cbase = x + ((size_t)nc << 16) + (size_t)col * 64;
    unsigned int* h = hist[wave];

    v4f va[16], vb[16];

#define ISSUE(buf, s)                                                             \
    _Pragma("unroll")                                                             \
    for (int k = 0; k < 16; ++k) {                                                \
        const int f = lane + (k << 6);        /* float4 idx 0..1023 */            \
        buf[k] = *reinterpret_cast<const v4f*>(                                   \
            cbase + (size_t)(s) * (64 * 256) + (size_t)(f >> 4) * 256 + (f & 15) * 4); \
    }

#define PROCESS(buf, s)                                                           \
    {                                                                             \
        float lmin = INFINITY, lmax = -INFINITY;                                  \
        _Pragma("unroll")                                                         \
        for (int k = 0; k < 16; ++k) {                                            \
            lmin = fminf(lmin, fminf(fminf(buf[k].x, buf[k].y),                   \
                                     fminf(buf[k].z, buf[k].w)));                 \
            lmax = fmaxf(lmax, fmaxf(fmaxf(buf[k].x, buf[k].y),                   \
                                     fmaxf(buf[k].z, buf[k].w)));                 \
        }                                                                         \
        _Pragma("unroll")                                                         \
        for (int off = 32; off > 0; off >>= 1) {                                  \
            lmin = fminf(lmin, __shfl_xor(lmin, off));                            \
            lmax = fmaxf(lmax, __shfl_xor(lmax, off));                            \
        }                                                                         \
        uint4 z; z.x = z.y = z.z = z.w = 0u;  /* same-wave DS ops in-order */     \
        reinterpret_cast<uint4*>(h)[lane] = z;                                    \
        const float width = (lmax - lmin) * (1.0f / NBINS);                       \
        const float wsafe = (width > 0.0f) ? width : 1.0f;                        \
        const float inv   = 1.0f / wsafe;                                         \
        const float coff  = -lmin * inv;                                          \
        _Pragma("unroll")                                                         \
        for (int k = 0; k < 16; ++k) {                                            \
            float vals[4] = {buf[k].x, buf[k].y, buf[k].z, buf[k].w};             \
            _Pragma("unroll")                                                     \
            for (int j = 0; j < 4; ++j) {                                         \
                /* arg >= -eps; trunc==floor for >=0, tiny negatives -> 0 */      \
                int bin = (int)fmaf(vals[j], inv, coff);                          \
                bin = min(bin, 255);                                              \
                atomicAdd(&h[bin], 1u);                                           \
            }                                                                     \
        }                                                                         \
        const uint4 c    = reinterpret_cast<const uint4*>(h)[lane];               \
        const float pden = inv * (1.0f / 4096.0f);  /* 1/(4096*wsafe) */          \
        const float p0 = (float)c.x * pden + EPSF;                                \
        const float p1 = (float)c.y * pden + EPSF;                                \
        const float p2 = (float)c.z * pden + EPSF;                                \
        const float p3 = (float)c.w * pden + EPSF;                                \
        float s_ = p0 + p1 + p2 + p3;                                             \
        _Pragma("unroll")                                                         \
        for (int off = 32; off > 0; off >>= 1) s_ += __shfl_xor(s_, off);         \
        const float itot = 1.0f / s_;                                             \
        const float q0 = p0 * itot, q1 = p1 * itot;                               \
        const float q2 = p2 * itot, q3 = p3 * itot;                               \
        float e = q0 * log2f(q0) + q1 * log2f(q1)                                 \
                + q2 * log2f(q2) + q3 * log2f(q3);                                \
        _Pragma("unroll")                                                         \
        for (int off = 32; off > 0; off >>= 1) e += __shfl_xor(e, off);           \
        if (lane == 0) ent_s[((s) << 2) + col] = -e;                              \
    }

    // ---- horizontal upsample weights (lane = x4), hoisted once ----
    const int x4 = lane;
    const int ix = (int)floorf(((x4 << 2) + 0.5f) * 0.015625f - 0.5f);
    const int x0 = max(ix, 0), x1 = min(ix + 1, 3);
    v4f wv[4];
#pragma unroll
    for (int j = 0; j < 4; ++j) {
        const float fx = ((x4 << 2) + j + 0.5f) * 0.015625f - 0.5f;
        const float wx = fx - floorf(fx);
        const float a  = 1.0f - wx, bb = wx;
        wv[j].x = ((x0 == 0) ? a : 0.0f) + ((x1 == 0) ? bb : 0.0f);
        wv[j].y = ((x0 == 1) ? a : 0.0f) + ((x1 == 1) ? bb : 0.0f);
        wv[j].z = ((x0 == 2) ? a : 0.0f) + ((x1 == 2) ? bb : 0.0f);
        wv[j].w = ((x0 == 3) ? a : 0.0f) + ((x1 == 3) ? bb : 0.0f);
    }
    const v4f* er = reinterpret_cast<const v4f*>(ent_s);   // 4 rows of 4
    v4f* out4 = reinterpret_cast<v4f*>(out) + ((size_t)nc << 14);

    // write nrows rows for THIS wave starting at ystart
#define WR(ystart, nrows)                                                         \
    _Pragma("unroll")                                                             \
    for (int i = 0; i < (nrows); ++i) {                                           \
        const int   y   = (ystart) + i;                                           \
        const float fy  = (y + 0.5f) * 0.015625f - 0.5f;                          \
        const float fiy = floorf(fy);                                             \
        const float wy  = fy - fiy;                                               \
        const int   iy  = (int)fiy;                                               \
        const int   y0  = max(iy, 0), y1 = min(iy + 1, 3);                        \
        const v4f r0 = er[y0];            /* uniform per wave -> broadcast */     \
        const v4f r1 = er[y1];                                                    \
        v4f rv = r0 * (1.0f - wy) + r1 * wy;                                      \
        v4f o;                                                                    \
        o.x = rv.x * wv[0].x + rv.y * wv[0].y + rv.z * wv[0].z + rv.w * wv[0].w;  \
        o.y = rv.x * wv[1].x + rv.y * wv[1].y + rv.z * wv[1].z + rv.w * wv[1].w;  \
        o.z = rv.x * wv[2].x + rv.y * wv[2].y + rv.z * wv[2].z + rv.w * wv[2].w;  \
        o.w = rv.x * wv[3].x + rv.y * wv[3].y + rv.z * wv[3].z + rv.w * wv[3].w;  \
        out4[(y << 6) + lane] = o;                                                \
    }

    // ---- schedule ----
    ISSUE(va, rA)
    ISSUE(vb, rB)
    PROCESS(va, rA)         // ent rows 0 (waves 0-3) and 3 (waves 4-7)
    __syncthreads();
    // edge bands: rows 0-31 need only ent r0; rows 224-255 only r3
    {
        const int ystart = (wave < 4) ? (wave << 3) : (192 + (wave << 3));
        WR(ystart, 8)
    }
    PROCESS(vb, rB)         // ent rows 1 and 2
    __syncthreads();
    WR(32 + wave * 24, 24)  // rows 32..223 (all ent rows available)

#undef ISSUE
#undef PROCESS
#undef WR
}

extern "C" void kernel_launch(void* const* d_in, const int* in_sizes, int n_in,
                              void* d_out, int out_size, void* d_ws, size_t ws_size,
                              hipStream_t stream) {
    const float* x   = (const float*)d_in[0];
    float*       out = (float*)d_out;
    fused_kernel<<<512, 512, 0, stream>>>(x, out);
}

// Round 17
// 43.381 us; speedup vs baseline: 1.3449x; 1.1902x over previous
//
#include <hip/hip_runtime.h>

#define NBINS 256
#define EPSF 1e-12f

typedef float v4f __attribute__((ext_vector_type(4)));

// R17 = R11 with rebalanced write chunks ONLY. 512 blocks x 256 threads,
// block = one (n,c) slice, wave w owns tile COLUMN w (tiles (s,w), s=0..3,
// register-double-buffered: 2 tile loads always in flight). Ent row s done
// after PROCESS s. Dependency (half-pixel bilinear, scale 64):
//   rows 0-95 need ent rows 0,1 | 96-159 need 1,2 | 160-255 need 2,3
// R11 wrote {64,64,128} rows at the 3 barriers; here {96,64,96} -> the pure
// write tail shrinks 128->96 rows, 16MB of writes move into the overlap
// region. Schedule/barriers/issue order byte-identical to R11 otherwise.
// Plain stores (R10), cheap fma binning (R8), wave-private hist (R5).
__global__ __launch_bounds__(256, 2) void fused_kernel(const float* __restrict__ x,
                                                       float* __restrict__ out) {
    const int nc   = blockIdx.x;              // 0..511
    const int t    = threadIdx.x;
    const int lane = t & 63;
    const int wave = t >> 6;                  // tile COLUMN

    __shared__ unsigned int hist[4][NBINS];   // 4 KB, wave-private
    __shared__ float ent_s[16];               // 4x4 entropy map, row-major

    const float* cbase = x + ((size_t)nc << 16) + (size_t)wave * 64;
    unsigned int* h = hist[wave];

    v4f va[16], vb[16];

#define ISSUE(buf, s)                                                             \
    _Pragma("unroll")                                                             \
    for (int k = 0; k < 16; ++k) {                                                \
        const int f = lane + (k << 6);        /* float4 idx 0..1023 */            \
        buf[k] = *reinterpret_cast<const v4f*>(                                   \
            cbase + (size_t)(s) * (64 * 256) + (size_t)(f >> 4) * 256 + (f & 15) * 4); \
    }

#define PROCESS(buf, s)                                                           \
    {                                                                             \
        float lmin = INFINITY, lmax = -INFINITY;                                  \
        _Pragma("unroll")                                                         \
        for (int k = 0; k < 16; ++k) {                                            \
            lmin = fminf(lmin, fminf(fminf(buf[k].x, buf[k].y),                   \
                                     fminf(buf[k].z, buf[k].w)));                 \
            lmax = fmaxf(lmax, fmaxf(fmaxf(buf[k].x, buf[k].y),                   \
                                     fmaxf(buf[k].z, buf[k].w)));                 \
        }                                                                         \
        _Pragma("unroll")                                                         \
        for (int off = 32; off > 0; off >>= 1) {                                  \
            lmin = fminf(lmin, __shfl_xor(lmin, off));                            \
            lmax = fmaxf(lmax, __shfl_xor(lmax, off));                            \
        }                                                                         \
        uint4 z; z.x = z.y = z.z = z.w = 0u;  /* same-wave DS ops in-order */     \
        reinterpret_cast<uint4*>(h)[lane] = z;                                    \
        const float width = (lmax - lmin) * (1.0f / NBINS);                       \
        const float wsafe = (width > 0.0f) ? width : 1.0f;                        \
        const float inv   = 1.0f / wsafe;                                         \
        const float coff  = -lmin * inv;                                          \
        _Pragma("unroll")                                                         \
        for (int k = 0; k < 16; ++k) {                                            \
            float vals[4] = {buf[k].x, buf[k].y, buf[k].z, buf[k].w};             \
            _Pragma("unroll")                                                     \
            for (int j = 0; j < 4; ++j) {                                         \
                /* arg >= -eps; trunc==floor for >=0, tiny negatives -> 0 */      \
                int bin = (int)fmaf(vals[j], inv, coff);                          \
                bin = min(bin, 255);                                              \
                atomicAdd(&h[bin], 1u);                                           \
            }                                                                     \
        }                                                                         \
        const uint4 c    = reinterpret_cast<const uint4*>(h)[lane];               \
        const float pden = inv * (1.0f / 4096.0f);  /* 1/(4096*wsafe) */          \
        const float p0 = (float)c.x * pden + EPSF;                                \
        const float p1 = (float)c.y * pden + EPSF;                                \
        const float p2 = (float)c.z * pden + EPSF;                                \
        const float p3 = (float)c.w * pden + EPSF;                                \
        float s_ = p0 + p1 + p2 + p3;                                             \
        _Pragma("unroll")                                                         \
        for (int off = 32; off > 0; off >>= 1) s_ += __shfl_xor(s_, off);         \
        const float itot = 1.0f / s_;                                             \
        const float q0 = p0 * itot, q1 = p1 * itot;                               \
        const float q2 = p2 * itot, q3 = p3 * itot;                               \
        float e = q0 * log2f(q0) + q1 * log2f(q1)                                 \
                + q2 * log2f(q2) + q3 * log2f(q3);                                \
        _Pragma("unroll")                                                         \
        for (int off = 32; off > 0; off >>= 1) e += __shfl_xor(e, off);           \
        if (lane == 0) ent_s[((s) << 2) + wave] = -e;                             \
    }

    // ---- horizontal upsample weights (lane = x4), hoisted once ----
    const int x4 = lane;
    const int ix = (int)floorf(((x4 << 2) + 0.5f) * 0.015625f - 0.5f);
    const int x0 = max(ix, 0), x1 = min(ix + 1, 3);
    v4f wv[4];
#pragma unroll
    for (int j = 0; j < 4; ++j) {
        const float fx = ((x4 << 2) + j + 0.5f) * 0.015625f - 0.5f;
        const float wx = fx - floorf(fx);
        const float a  = 1.0f - wx, bb = wx;
        wv[j].x = ((x0 == 0) ? a : 0.0f) + ((x1 == 0) ? bb : 0.0f);
        wv[j].y = ((x0 == 1) ? a : 0.0f) + ((x1 == 1) ? bb : 0.0f);
        wv[j].z = ((x0 == 2) ? a : 0.0f) + ((x1 == 2) ? bb : 0.0f);
        wv[j].w = ((x0 == 3) ? a : 0.0f) + ((x1 == 3) ? bb : 0.0f);
    }
    const v4f* er = reinterpret_cast<const v4f*>(ent_s);   // 4 rows of 4
    v4f* out4 = reinterpret_cast<v4f*>(out) + ((size_t)nc << 14);

    // write nrows/4 rows per wave starting at ystart (wave-strided chunks)
#define WR(ystart, nrows)                                                         \
    _Pragma("unroll")                                                             \
    for (int i = 0; i < (nrows) / 4; ++i) {                                       \
        const int   y   = (ystart) + wave * ((nrows) / 4) + i;                    \
        const float fy  = (y + 0.5f) * 0.015625f - 0.5f;                          \
        const float fiy = floorf(fy);                                             \
        const float wy  = fy - fiy;                                               \
        const int   iy  = (int)fiy;                                               \
        const int   y0  = max(iy, 0), y1 = min(iy + 1, 3);                        \
        const v4f r0 = er[y0];            /* uniform per wave -> broadcast */     \
        const v4f r1 = er[y1];                                                    \
        v4f rv = r0 * (1.0f - wy) + r1 * wy;                                      \
        v4f o;                                                                    \
        o.x = rv.x * wv[0].x + rv.y * wv[0].y + rv.z * wv[0].z + rv.w * wv[0].w;  \
        o.y = rv.x * wv[1].x + rv.y * wv[1].y + rv.z * wv[1].z + rv.w * wv[1].w;  \
        o.z = rv.x * wv[2].x + rv.y * wv[2].y + rv.z * wv[2].z + rv.w * wv[2].w;  \
        o.w = rv.x * wv[3].x + rv.y * wv[3].y + rv.z * wv[3].z + rv.w * wv[3].w;  \
        out4[(y << 6) + lane] = o;                                                \
    }

    // ---- pipelined schedule (identical to R11), rebalanced write chunks ----
    ISSUE(va, 0)
    ISSUE(vb, 1)
    PROCESS(va, 0)          // ent row 0
    ISSUE(va, 2)
    PROCESS(vb, 1)          // ent row 1
    ISSUE(vb, 3)
    __syncthreads();        // ent rows 0,1 complete across all waves
    WR(0, 96)               // rows 0..95    (need ent rows 0,1)
    PROCESS(va, 2)          // ent row 2
    __syncthreads();        // ent row 2 complete
    WR(96, 64)              // rows 96..159  (need ent rows 1,2)
    PROCESS(vb, 3)          // ent row 3
    __syncthreads();        // ent row 3 complete
    WR(160, 96)             // rows 160..255 (need ent rows 2,3)

#undef ISSUE
#undef PROCESS
#undef WR
}

extern "C" void kernel_launch(void* const* d_in, const int* in_sizes, int n_in,
                              void* d_out, int out_size, void* d_ws, size_t ws_size,
                              hipStream_t stream) {
    const float* x   = (const float*)d_in[0];
    float*       out = (float*)d_out;
    fused_kernel<<<512, 256, 0, stream>>>(x, out);
}